// Round 1
// baseline (5411.226 us; speedup 1.0000x reference)
//
#include <hip/hip_runtime.h>
#include <math.h>

// ---------------------------------------------------------------------------
// AttnModel3: B=256, N=64, F=64, S=130.
// Factorization: x differs per action n only in column s=129, so
//   q_f(n) = ( U_f + c_f(n)*W[129,:] - m_f(n)*A_f ) * inv_f(n) + B_f
// with U=(alpha1 .* x_base)@W per-b, A=alpha1@W, B=beta1@W+b global.
// k0: A,B,AW(=alpha2.*Wlin),Pa,Cc   k1: per-b U,S1,S2   k2: per-(b,n) attn.
// sim/ao via bf16 MFMA 16x16x32; softmax + output stats fully in-register.
// ---------------------------------------------------------------------------

typedef __attribute__((ext_vector_type(4))) float f32x4;
typedef __attribute__((ext_vector_type(8))) short bf16x8;

#define EPSF 1e-6f
#define INVS 0.0877058019307029f /* 1/sqrt(130) */

__device__ __forceinline__ unsigned short f2bf(float f) {
  unsigned int u = __builtin_bit_cast(unsigned int, f);
  u += 0x7FFFu + ((u >> 16) & 1u);
  return (unsigned short)(u >> 16);
}

// ---------------- kernel 0: global precomputes ----------------
__global__ __launch_bounds__(256) void k0(
    const float* __restrict__ alpha1, const float* __restrict__ beta1,
    const float* __restrict__ alpha2, const float* __restrict__ beta2,
    const float* __restrict__ Wq, const float* __restrict__ bq,
    const float* __restrict__ Wk, const float* __restrict__ bk,
    const float* __restrict__ Wv, const float* __restrict__ bv,
    const float* __restrict__ Wlin, const float* __restrict__ blin,
    float* __restrict__ Aws, float* __restrict__ Bws,
    float* __restrict__ AWw, float* __restrict__ Paw, float* __restrict__ Ccw)
{
  __shared__ float sbuf[64 * 132];
  __shared__ float Wbuf[130 * 144];
  int blk = blockIdx.x, tid = threadIdx.x;
  if (blk < 6) {
    int m = blk >> 1, isB = blk & 1;
    const float* src  = isB ? beta1 : alpha1;
    const float* W    = (m == 0) ? Wq : (m == 1) ? Wk : Wv;
    const float* bias = (m == 0) ? bq : (m == 1) ? bk : bv;
    for (int e = tid; e < 8320; e += 256) { int f = e / 130, s = e - f * 130; sbuf[f * 132 + s] = src[e]; }
    for (int e = tid; e < 16900; e += 256) { int s = e / 130, t = e - s * 130; Wbuf[s * 144 + t] = W[e]; }
    __syncthreads();
    int ty = tid >> 4, tx = tid & 15;
    float acc[4][9] = {};
    for (int s = 0; s < 130; ++s) {
      float g0 = sbuf[(ty * 4 + 0) * 132 + s];
      float g1 = sbuf[(ty * 4 + 1) * 132 + s];
      float g2 = sbuf[(ty * 4 + 2) * 132 + s];
      float g3 = sbuf[(ty * 4 + 3) * 132 + s];
#pragma unroll
      for (int c = 0; c < 9; ++c) {
        float wv = Wbuf[s * 144 + tx + 16 * c];
        acc[0][c] += g0 * wv; acc[1][c] += g1 * wv;
        acc[2][c] += g2 * wv; acc[3][c] += g3 * wv;
      }
    }
    float* dst = (isB ? Bws : Aws) + m * 8320;
#pragma unroll
    for (int i = 0; i < 4; ++i)
      for (int c = 0; c < 9; ++c) {
        int t = tx + 16 * c;
        if (t < 130) dst[(ty * 4 + i) * 130 + t] = acc[i][c] + (isB ? bias[t] : 0.f);
      }
  } else if (blk == 6) {
    if (tid < 64) {
      int f = tid;
      float pa = 0.f, cc = 0.f;
      for (int s = 0; s < 130; ++s) {
        float wl = Wlin[f * 130 + s];
        float aw = alpha2[f * 130 + s] * wl;
        AWw[f * 130 + s] = aw;
        pa += aw;
        cc += beta2[f * 130 + s] * wl;
      }
      Paw[f] = pa;
#pragma unroll
      for (int msk = 1; msk <= 32; msk <<= 1) cc += __shfl_xor(cc, msk, 64);
      if (f == 0) Ccw[0] = cc + blin[0];
    }
  }
}

// ---------------- kernel 1: per-b U, S1, S2 ----------------
__global__ __launch_bounds__(256) void k1(
    const float* __restrict__ h1, const float* __restrict__ h2,
    const float* __restrict__ sp, const float* __restrict__ alpha1,
    const float* __restrict__ Wq, const float* __restrict__ Wk, const float* __restrict__ Wv,
    float* __restrict__ Uws, float* __restrict__ S1g, float* __restrict__ S2g)
{
  __shared__ float gbuf[64 * 132];
  __shared__ float Wbuf[130 * 144];
  __shared__ float ps[2][256];
  int b = blockIdx.x, tid = threadIdx.x;
  float s1 = 0.f, s2 = 0.f;
  for (int idx = tid; idx < 8256; idx += 256) {  // 129*64, f = idx&63 constant/thread
    int s = idx >> 6, f = idx & 63;
    float x = (s < 64)  ? h1[((size_t)(b * 64 + s)) * 64 + f]
            : (s < 128) ? h2[((size_t)(b * 64 + (s - 64))) * 64 + f]
                        : sp[b * 64 + f];
    gbuf[f * 132 + s] = alpha1[f * 130 + s] * x;
    s1 += x; s2 += x * x;
  }
  ps[0][tid] = s1; ps[1][tid] = s2;
  __syncthreads();
  if (tid < 64) {
    S1g[b * 64 + tid] = ps[0][tid] + ps[0][tid + 64] + ps[0][tid + 128] + ps[0][tid + 192];
    S2g[b * 64 + tid] = ps[1][tid] + ps[1][tid + 64] + ps[1][tid + 128] + ps[1][tid + 192];
  }
  int ty = tid >> 4, tx = tid & 15;
  for (int m = 0; m < 3; ++m) {
    const float* W = (m == 0) ? Wq : (m == 1) ? Wk : Wv;
    __syncthreads();
    for (int e = tid; e < 16900; e += 256) { int s = e / 130, t = e - s * 130; Wbuf[s * 144 + t] = W[e]; }
    __syncthreads();
    float acc[4][9] = {};
    for (int s = 0; s < 129; ++s) {  // K = 129 (col 129 handled per-n)
      float g0 = gbuf[(ty * 4 + 0) * 132 + s];
      float g1 = gbuf[(ty * 4 + 1) * 132 + s];
      float g2 = gbuf[(ty * 4 + 2) * 132 + s];
      float g3 = gbuf[(ty * 4 + 3) * 132 + s];
#pragma unroll
      for (int c = 0; c < 9; ++c) {
        float wv = Wbuf[s * 144 + tx + 16 * c];
        acc[0][c] += g0 * wv; acc[1][c] += g1 * wv;
        acc[2][c] += g2 * wv; acc[3][c] += g3 * wv;
      }
    }
    float* U = Uws + ((size_t)(m * 256 + b)) * 8320;
#pragma unroll
    for (int i = 0; i < 4; ++i)
      for (int c = 0; c < 9; ++c) {
        int t = tx + 16 * c;
        if (t < 130) U[(ty * 4 + i) * 130 + t] = acc[i][c];
      }
  }
}

// ---------------- kernel 2: per-(b,n) attention ----------------
__global__ __launch_bounds__(256, 2) void k2(
    const float* __restrict__ h2, const float* __restrict__ alpha1,
    const float* __restrict__ Uws, const float* __restrict__ Aws, const float* __restrict__ Bws,
    const float* __restrict__ S1g, const float* __restrict__ S2g,
    const float* __restrict__ AWw, const float* __restrict__ Paw, const float* __restrict__ Ccw,
    const float* __restrict__ Wq, const float* __restrict__ Wk, const float* __restrict__ Wv,
    float* __restrict__ out)
{
  __shared__ __align__(16) unsigned short qb[64 * 168];  // rows f, cols t (K-pad to 160)
  __shared__ __align__(16) unsigned short kb[64 * 168];
  __shared__ __align__(16) unsigned short vT[144 * 72];  // rows s(144), cols j(64)
  __shared__ __align__(16) unsigned short pb[64 * 72];
  __shared__ float w129[3][132];
  __shared__ float S1l[64], S2l[64], ael[64];
  __shared__ float mrow[64], irow[64], crow[64];
  __shared__ float redbuf[4];

  int b = blockIdx.x, tid = threadIdx.x;
  int w = tid >> 6, l = tid & 63, l15 = l & 15, l4 = l >> 4;

  if (tid < 132) {
    w129[0][tid] = (tid < 130) ? Wq[129 * 130 + tid] : 0.f;
    w129[1][tid] = (tid < 130) ? Wk[129 * 130 + tid] : 0.f;
    w129[2][tid] = (tid < 130) ? Wv[129 * 130 + tid] : 0.f;
  }
  if (tid < 64) {
    S1l[tid] = S1g[b * 64 + tid];
    S2l[tid] = S2g[b * 64 + tid];
    ael[tid] = alpha1[tid * 130 + 129];
  }
  for (int i = tid; i < 14 * 72; i += 256) vT[130 * 72 + i] = 0;  // zero pad rows
  float ccv = Ccw[0];
  __syncthreads();

  const float* uqB = Uws + ((size_t)(0 * 256 + b)) * 8320;
  const float* ukB = Uws + ((size_t)(1 * 256 + b)) * 8320;
  const float* uvB = Uws + ((size_t)(2 * 256 + b)) * 8320;
  const float* av2 = Aws + 2 * 8320;
  const float* bv2 = Bws + 2 * 8320;

  for (int n = 0; n < 64; ++n) {
    if (tid < 64) {
      float a  = h2[((size_t)(b * 64 + n)) * 64 + tid];
      float m  = (S1l[tid] + a) * (1.f / 130.f);
      float e2 = (S2l[tid] + a * a) * (1.f / 130.f);
      float sd = sqrtf(fmaxf(e2 - m * m, 0.f));
      mrow[tid] = m;
      irow[tid] = 1.f / (sd + EPSF);
      crow[tid] = ael[tid] * a;
    }
    __syncthreads();

    // ---- generate q, k (bf16, K-padded with zeros to 160) ----
    {
      int f = tid >> 2, c3 = tid & 3;
      float m = mrow[f], inv = irow[f], c = crow[f];
      const float* uq = uqB + f * 130;
      const float* uk = ukB + f * 130;
      const float* aq = Aws + 0 * 8320 + f * 130;
      const float* ak = Aws + 1 * 8320 + f * 130;
      const float* Bq = Bws + 0 * 8320 + f * 130;
      const float* Bk = Bws + 1 * 8320 + f * 130;
      int t0 = c3 * 40;
      for (int j8 = 0; j8 < 5; ++j8) {
        bf16x8 qv, kv;
#pragma unroll
        for (int e = 0; e < 8; ++e) {
          int t = t0 + j8 * 8 + e;
          float q = 0.f, k = 0.f;
          if (t < 130) {
            q = (uq[t] + c * w129[0][t] - m * aq[t]) * inv + Bq[t];
            k = (uk[t] + c * w129[1][t] - m * ak[t]) * inv + Bk[t];
          }
          qv[e] = (short)f2bf(q);
          kv[e] = (short)f2bf(k);
        }
        *(bf16x8*)&qb[f * 168 + t0 + j8 * 8] = qv;
        *(bf16x8*)&kb[f * 168 + t0 + j8 * 8] = kv;
      }
    }
    // ---- generate v^T (threads 0..129 each own one s-column) ----
    if (tid < 130) {
      int t = tid;
      float wv = w129[2][t];
      for (int f8 = 0; f8 < 8; ++f8) {
        bf16x8 vv;
#pragma unroll
        for (int e = 0; e < 8; ++e) {
          int f = f8 * 8 + e;
          float v = (uvB[f * 130 + t] + crow[f] * wv - mrow[f] * av2[f * 130 + t]) * irow[f]
                    + bv2[f * 130 + t];
          vv[e] = (short)f2bf(v);
        }
        *(bf16x8*)&vT[t * 72 + f8 * 8] = vv;
      }
    }
    __syncthreads();

    // ---- sim = q k^T (wave w owns rows [16w,16w+16)) ----
    f32x4 sacc[4] = {};
    {
      const unsigned short* qrow = &qb[(w * 16 + l15) * 168 + l4 * 8];
#pragma unroll
      for (int kk = 0; kk < 5; ++kk) {
        bf16x8 avv = *(const bf16x8*)&qrow[kk * 32];
#pragma unroll
        for (int cf = 0; cf < 4; ++cf) {
          bf16x8 bvv = *(const bf16x8*)&kb[(cf * 16 + l15) * 168 + l4 * 8 + kk * 32];
          sacc[cf] = __builtin_amdgcn_mfma_f32_16x16x32_bf16(avv, bvv, sacc[cf], 0, 0, 0);
        }
      }
    }
    // ---- in-register softmax over full rows ----
    float prob[4][4];
#pragma unroll
    for (int r = 0; r < 4; ++r) {
      float mx = fmaxf(fmaxf(sacc[0][r], sacc[1][r]), fmaxf(sacc[2][r], sacc[3][r]));
#pragma unroll
      for (int msk = 1; msk <= 8; msk <<= 1) mx = fmaxf(mx, __shfl_xor(mx, msk, 64));
      float ssum = 0.f;
#pragma unroll
      for (int cf = 0; cf < 4; ++cf) {
        float e = __expf((sacc[cf][r] - mx) * INVS);
        prob[cf][r] = e;
        ssum += e;
      }
#pragma unroll
      for (int msk = 1; msk <= 8; msk <<= 1) ssum += __shfl_xor(ssum, msk, 64);
      float is = 1.f / ssum;
#pragma unroll
      for (int cf = 0; cf < 4; ++cf) prob[cf][r] *= is;
    }
#pragma unroll
    for (int cf = 0; cf < 4; ++cf)
#pragma unroll
      for (int r = 0; r < 4; ++r)
        pb[(w * 16 + l4 * 4 + r) * 72 + cf * 16 + l15] = f2bf(prob[cf][r]);
    // pb rows are produced and consumed by the same wave -> no barrier needed.

    // ---- ao = p v ----
    f32x4 aoacc[9] = {};
    {
      const unsigned short* prow = &pb[(w * 16 + l15) * 72 + l4 * 8];
#pragma unroll
      for (int kk = 0; kk < 2; ++kk) {
        bf16x8 avv = *(const bf16x8*)&prow[kk * 32];
#pragma unroll
        for (int sf = 0; sf < 9; ++sf) {
          bf16x8 bvv = *(const bf16x8*)&vT[(sf * 16 + l15) * 72 + l4 * 8 + kk * 32];
          aoacc[sf] = __builtin_amdgcn_mfma_f32_16x16x32_bf16(avv, bvv, aoacc[sf], 0, 0, 0);
        }
      }
    }
    // ---- fused Norm2 + Wlin projection via row statistics ----
    float csum = 0.f;
#pragma unroll
    for (int r = 0; r < 4; ++r) {
      int row = w * 16 + l4 * 4 + r;
      float s1 = 0.f, s2 = 0.f, sdt = 0.f;
#pragma unroll
      for (int sf = 0; sf < 9; ++sf) {
        int col = sf * 16 + l15;
        float v = aoacc[sf][r];
        if (col < 130) {
          s1 += v;
          s2 += v * v;
          sdt += v * AWw[row * 130 + col];
        }
      }
#pragma unroll
      for (int msk = 1; msk <= 8; msk <<= 1) {
        s1 += __shfl_xor(s1, msk, 64);
        s2 += __shfl_xor(s2, msk, 64);
        sdt += __shfl_xor(sdt, msk, 64);
      }
      float mz  = 2.f * s1 * (1.f / 130.f);        // mean of z = 2*ao
      float ez2 = 4.f * s2 * (1.f / 130.f);
      float sg  = sqrtf(fmaxf(ez2 - mz * mz, 0.f));
      float i2  = 1.f / (sg + EPSF);
      csum += (2.f * sdt - mz * Paw[row]) * i2;
    }
    float tsum = (l15 == 0) ? csum : 0.f;
#pragma unroll
    for (int msk = 1; msk <= 32; msk <<= 1) tsum += __shfl_xor(tsum, msk, 64);
    if (l == 0) redbuf[w] = tsum;
    __syncthreads();
    if (tid == 0) out[b * 64 + n] = redbuf[0] + redbuf[1] + redbuf[2] + redbuf[3] + ccv;
  }
}

// ---------------- host launch ----------------
extern "C" void kernel_launch(void* const* d_in, const int* in_sizes, int n_in,
                              void* d_out, int out_size, void* d_ws, size_t ws_size,
                              hipStream_t stream) {
  const float* sp     = (const float*)d_in[0];
  const float* h1     = (const float*)d_in[1];
  const float* h2     = (const float*)d_in[2];
  const float* Wq     = (const float*)d_in[3];
  const float* bq     = (const float*)d_in[4];
  const float* Wk     = (const float*)d_in[5];
  const float* bk     = (const float*)d_in[6];
  const float* Wv     = (const float*)d_in[7];
  const float* bv     = (const float*)d_in[8];
  const float* alpha1 = (const float*)d_in[9];
  const float* beta1  = (const float*)d_in[10];
  const float* alpha2 = (const float*)d_in[11];
  const float* beta2  = (const float*)d_in[12];
  const float* Wlin   = (const float*)d_in[13];
  const float* blin   = (const float*)d_in[14];
  float* out = (float*)d_out;

  float* w   = (float*)d_ws;
  float* Uws = w;                    // 3*256*8320 = 6,389,760
  float* S1g = Uws + 6389760;        // 16384
  float* S2g = S1g + 16384;          // 16384
  float* Aws = S2g + 16384;          // 24960
  float* Bws = Aws + 24960;          // 24960
  float* AWw = Bws + 24960;          // 8320
  float* Paw = AWw + 8320;           // 64
  float* Ccw = Paw + 64;             // 1   -> total ~25.9 MB

  k0<<<dim3(7), dim3(256), 0, stream>>>(alpha1, beta1, alpha2, beta2,
                                        Wq, bq, Wk, bk, Wv, bv, Wlin, blin,
                                        Aws, Bws, AWw, Paw, Ccw);
  k1<<<dim3(256), dim3(256), 0, stream>>>(h1, h2, sp, alpha1, Wq, Wk, Wv,
                                          Uws, S1g, S2g);
  k2<<<dim3(256), dim3(256), 0, stream>>>(h2, alpha1, Uws, Aws, Bws, S1g, S2g,
                                          AWw, Paw, Ccw, Wq, Wk, Wv, out);
}

// Round 2
// 1526.769 us; speedup vs baseline: 3.5442x; 3.5442x over previous
//
#include <hip/hip_runtime.h>
#include <math.h>

// ---------------------------------------------------------------------------
// AttnModel3: B=256, N=64, F=64, S=130.
//   q_f(n) = ( U_f + c_f(n)*W[129,:] - m_f(n)*A_f ) * inv_f(n) + B_f
// k0: A,B (q/k row-major, v transposed), AW, Pa, Cc
// k1: per-b U (q/k row-major, v transposed), S1, S2
// k2: grid 2048 = (8 n-tiles x 256 b), 512 thr, XCD-co-located per b.
// ---------------------------------------------------------------------------

typedef __attribute__((ext_vector_type(4))) float f32x4;
typedef __attribute__((ext_vector_type(2))) float f32x2;
typedef __attribute__((ext_vector_type(8))) short bf16x8;

#define EPSF 1e-6f
#define INVS 0.0877058019307029f /* 1/sqrt(130) */

__device__ __forceinline__ unsigned short f2bf(float f) {
  unsigned int u = __builtin_bit_cast(unsigned int, f);
  u += 0x7FFFu + ((u >> 16) & 1u);
  return (unsigned short)(u >> 16);
}

// ---------------- kernel 0: global precomputes ----------------
__global__ __launch_bounds__(256) void k0(
    const float* __restrict__ alpha1, const float* __restrict__ beta1,
    const float* __restrict__ alpha2, const float* __restrict__ beta2,
    const float* __restrict__ Wq, const float* __restrict__ bq,
    const float* __restrict__ Wk, const float* __restrict__ bk,
    const float* __restrict__ Wv, const float* __restrict__ bv,
    const float* __restrict__ Wlin, const float* __restrict__ blin,
    float* __restrict__ Aws, float* __restrict__ Bws,
    float* __restrict__ AWw, float* __restrict__ Paw, float* __restrict__ Ccw)
{
  __shared__ float sbuf[64 * 132];
  __shared__ float Wbuf[130 * 144];
  int blk = blockIdx.x, tid = threadIdx.x;
  if (blk < 6) {
    int m = blk >> 1, isB = blk & 1;
    const float* src  = isB ? beta1 : alpha1;
    const float* W    = (m == 0) ? Wq : (m == 1) ? Wk : Wv;
    const float* bias = (m == 0) ? bq : (m == 1) ? bk : bv;
    for (int e = tid; e < 8320; e += 256) { int f = e / 130, s = e - f * 130; sbuf[f * 132 + s] = src[e]; }
    for (int e = tid; e < 16900; e += 256) { int s = e / 130, t = e - s * 130; Wbuf[s * 144 + t] = W[e]; }
    __syncthreads();
    int ty = tid >> 4, tx = tid & 15;
    float acc[4][9] = {};
    for (int s = 0; s < 130; ++s) {
      float g0 = sbuf[(ty * 4 + 0) * 132 + s];
      float g1 = sbuf[(ty * 4 + 1) * 132 + s];
      float g2 = sbuf[(ty * 4 + 2) * 132 + s];
      float g3 = sbuf[(ty * 4 + 3) * 132 + s];
#pragma unroll
      for (int c = 0; c < 9; ++c) {
        float wv = Wbuf[s * 144 + tx + 16 * c];
        acc[0][c] += g0 * wv; acc[1][c] += g1 * wv;
        acc[2][c] += g2 * wv; acc[3][c] += g3 * wv;
      }
    }
    float* dst = (isB ? Bws : Aws) + m * 8320;
#pragma unroll
    for (int i = 0; i < 4; ++i)
      for (int c = 0; c < 9; ++c) {
        int t = tx + 16 * c;
        if (t < 130) {
          float val = acc[i][c] + (isB ? bias[t] : 0.f);
          if (m == 2) dst[t * 64 + (ty * 4 + i)] = val;   // v: transposed [t][f]
          else        dst[(ty * 4 + i) * 130 + t] = val;  // q/k: [f][t]
        }
      }
  } else if (blk == 6) {
    if (tid < 64) {
      int f = tid;
      float pa = 0.f, cc = 0.f;
      for (int s = 0; s < 130; ++s) {
        float wl = Wlin[f * 130 + s];
        float aw = alpha2[f * 130 + s] * wl;
        AWw[f * 130 + s] = aw;
        pa += aw;
        cc += beta2[f * 130 + s] * wl;
      }
      Paw[f] = pa;
#pragma unroll
      for (int msk = 1; msk <= 32; msk <<= 1) cc += __shfl_xor(cc, msk, 64);
      if (f == 0) Ccw[0] = cc + blin[0];
    }
  }
}

// ---------------- kernel 1: per-b U, S1, S2 ----------------
__global__ __launch_bounds__(256) void k1(
    const float* __restrict__ h1, const float* __restrict__ h2,
    const float* __restrict__ sp, const float* __restrict__ alpha1,
    const float* __restrict__ Wq, const float* __restrict__ Wk, const float* __restrict__ Wv,
    float* __restrict__ Uws, float* __restrict__ S1g, float* __restrict__ S2g)
{
  __shared__ float gbuf[64 * 132];
  __shared__ float Wbuf[130 * 144];
  __shared__ float ps[2][256];
  int b = blockIdx.x, tid = threadIdx.x;
  float s1 = 0.f, s2 = 0.f;
  for (int idx = tid; idx < 8256; idx += 256) {  // 129*64, f = idx&63 constant/thread
    int s = idx >> 6, f = idx & 63;
    float x = (s < 64)  ? h1[((size_t)(b * 64 + s)) * 64 + f]
            : (s < 128) ? h2[((size_t)(b * 64 + (s - 64))) * 64 + f]
                        : sp[b * 64 + f];
    gbuf[f * 132 + s] = alpha1[f * 130 + s] * x;
    s1 += x; s2 += x * x;
  }
  ps[0][tid] = s1; ps[1][tid] = s2;
  __syncthreads();
  if (tid < 64) {
    S1g[b * 64 + tid] = ps[0][tid] + ps[0][tid + 64] + ps[0][tid + 128] + ps[0][tid + 192];
    S2g[b * 64 + tid] = ps[1][tid] + ps[1][tid + 64] + ps[1][tid + 128] + ps[1][tid + 192];
  }
  int ty = tid >> 4, tx = tid & 15;
  for (int m = 0; m < 3; ++m) {
    const float* W = (m == 0) ? Wq : (m == 1) ? Wk : Wv;
    __syncthreads();
    for (int e = tid; e < 16900; e += 256) { int s = e / 130, t = e - s * 130; Wbuf[s * 144 + t] = W[e]; }
    __syncthreads();
    float acc[4][9] = {};
    for (int s = 0; s < 129; ++s) {  // K = 129 (col 129 handled per-n)
      float g0 = gbuf[(ty * 4 + 0) * 132 + s];
      float g1 = gbuf[(ty * 4 + 1) * 132 + s];
      float g2 = gbuf[(ty * 4 + 2) * 132 + s];
      float g3 = gbuf[(ty * 4 + 3) * 132 + s];
#pragma unroll
      for (int c = 0; c < 9; ++c) {
        float wv = Wbuf[s * 144 + tx + 16 * c];
        acc[0][c] += g0 * wv; acc[1][c] += g1 * wv;
        acc[2][c] += g2 * wv; acc[3][c] += g3 * wv;
      }
    }
    float* U = Uws + ((size_t)(m * 256 + b)) * 8320;
#pragma unroll
    for (int i = 0; i < 4; ++i)
      for (int c = 0; c < 9; ++c) {
        int t = tx + 16 * c;
        if (t < 130) {
          if (m == 2) U[t * 64 + (ty * 4 + i)] = acc[i][c];  // transposed
          else        U[(ty * 4 + i) * 130 + t] = acc[i][c];
        }
      }
  }
}

// ---------------- kernel 2: per-(b, n-tile) attention ----------------
__global__ __launch_bounds__(512, 4) void k2(
    const float* __restrict__ h2, const float* __restrict__ alpha1,
    const float* __restrict__ Uws, const float* __restrict__ Aws, const float* __restrict__ Bws,
    const float* __restrict__ S1g, const float* __restrict__ S2g,
    const float* __restrict__ AWw, const float* __restrict__ Paw, const float* __restrict__ Ccw,
    const float* __restrict__ Wq, const float* __restrict__ Wk, const float* __restrict__ Wv,
    float* __restrict__ out)
{
  __shared__ __align__(16) unsigned short qb[64 * 168];  // rows f, cols t (K-pad to 160)
  __shared__ __align__(16) unsigned short kb[64 * 168];
  __shared__ __align__(16) unsigned short vT[144 * 72];  // rows s(144), cols j(64)
  __shared__ __align__(16) unsigned short pb[64 * 72];
  __shared__ __align__(16) float w129[3][132];
  __shared__ __align__(16) float S1l[64], S2l[64], ael[64];
  __shared__ __align__(16) float mrow[64], irow[64], crow[64];
  __shared__ float redbuf[4];

  // XCD co-location: all 8 n-tile blocks of a given b land on the same XCD
  // (dispatch round-robins flat id % 8). Bijective over 2048 blocks.
  int flat = blockIdx.x;
  int xcd = flat & 7, jj = flat >> 3;       // jj in 0..255
  int b  = ((jj >> 3) << 3) + xcd;          // 32 b's per XCD
  int n0 = (jj & 7) * 8;                    // 8 actions per block

  int tid = threadIdx.x;
  int w = tid >> 6, l = tid & 63, l15 = l & 15, l4 = l >> 4;

  if (tid < 132) {
    w129[0][tid] = (tid < 130) ? Wq[129 * 130 + tid] : 0.f;
    w129[1][tid] = (tid < 130) ? Wk[129 * 130 + tid] : 0.f;
    w129[2][tid] = (tid < 130) ? Wv[129 * 130 + tid] : 0.f;
  }
  if (tid >= 256 && tid < 320) {
    int f = tid - 256;
    S1l[f] = S1g[b * 64 + f];
    S2l[f] = S2g[b * 64 + f];
    ael[f] = alpha1[f * 130 + 129];
  }
  for (int i = tid; i < 14 * 72; i += 512) vT[130 * 72 + i] = 0;  // zero pad rows
  float ccv = Ccw[0];
  __syncthreads();

  const float* uqB = Uws + ((size_t)(0 * 256 + b)) * 8320;
  const float* ukB = Uws + ((size_t)(1 * 256 + b)) * 8320;
  const float* uvT = Uws + ((size_t)(2 * 256 + b)) * 8320;  // [t][f]
  const float* aqB = Aws + 0 * 8320;
  const float* akB = Aws + 1 * 8320;
  const float* avT = Aws + 2 * 8320;                        // [t][f]
  const float* bqB = Bws + 0 * 8320;
  const float* bkB = Bws + 1 * 8320;
  const float* bvT = Bws + 2 * 8320;                        // [t][f]

  auto genv = [&](int t, int f8) {
    float wv = w129[2][t];
    int o = t * 64 + f8 * 8;
    f32x4 u0 = *(const f32x4*)&uvT[o],     u1 = *(const f32x4*)&uvT[o + 4];
    f32x4 a0 = *(const f32x4*)&avT[o],     a1 = *(const f32x4*)&avT[o + 4];
    f32x4 b0 = *(const f32x4*)&bvT[o],     b1 = *(const f32x4*)&bvT[o + 4];
    f32x4 m0 = *(const f32x4*)&mrow[f8*8], m1 = *(const f32x4*)&mrow[f8*8+4];
    f32x4 i0 = *(const f32x4*)&irow[f8*8], i1 = *(const f32x4*)&irow[f8*8+4];
    f32x4 c0 = *(const f32x4*)&crow[f8*8], c1 = *(const f32x4*)&crow[f8*8+4];
    bf16x8 vv;
#pragma unroll
    for (int e = 0; e < 4; ++e) {
      float v = (u0[e] + c0[e] * wv - m0[e] * a0[e]) * i0[e] + b0[e];
      vv[e] = (short)f2bf(v);
    }
#pragma unroll
    for (int e = 0; e < 4; ++e) {
      float v = (u1[e] + c1[e] * wv - m1[e] * a1[e]) * i1[e] + b1[e];
      vv[4 + e] = (short)f2bf(v);
    }
    *(bf16x8*)&vT[t * 72 + f8 * 8] = vv;
  };

  for (int ni = 0; ni < 8; ++ni) {
    int n = n0 + ni;
    if (tid < 64) {
      float a  = h2[((size_t)(b * 64 + n)) * 64 + tid];
      float m  = (S1l[tid] + a) * (1.f / 130.f);
      float e2 = (S2l[tid] + a * a) * (1.f / 130.f);
      float sd = sqrtf(fmaxf(e2 - m * m, 0.f));
      mrow[tid] = m;
      irow[tid] = 1.f / (sd + EPSF);
      crow[tid] = ael[tid] * a;
    }
    __syncthreads();

    // ---- generate q (tid<256) / k (tid>=256), bf16, K-padded to 160 ----
    {
      int isK = tid >> 8;
      int t5 = tid & 255;
      int f = t5 >> 2, c3 = t5 & 3, t0 = c3 * 40;
      float m = mrow[f], inv = irow[f], c = crow[f];
      const float* ub = (isK ? ukB : uqB) + f * 130;
      const float* ab = (isK ? akB : aqB) + f * 130;
      const float* bb = (isK ? bkB : bqB) + f * 130;
      const float* wrow = w129[isK];
      unsigned short* dst = (isK ? kb : qb) + f * 168;
      for (int j8 = 0; j8 < 5; ++j8) {
        int tb = t0 + j8 * 8;
        bf16x8 ov;
#pragma unroll
        for (int p = 0; p < 4; ++p) {
          int t = tb + p * 2;
          float v0 = 0.f, v1 = 0.f;
          if (t < 130) {
            f32x2 u2 = *(const f32x2*)&ub[t];
            f32x2 a2 = *(const f32x2*)&ab[t];
            f32x2 b2 = *(const f32x2*)&bb[t];
            v0 = (u2[0] + c * wrow[t] - m * a2[0]) * inv + b2[0];
            v1 = (t + 1 < 130) ? (u2[1] + c * wrow[t + 1] - m * a2[1]) * inv + b2[1] : 0.f;
          }
          ov[p * 2]     = (short)f2bf(v0);
          ov[p * 2 + 1] = (short)f2bf(v1);
        }
        *(bf16x8*)&dst[tb] = ov;
      }
    }
    // ---- generate v^T: 1040 octets over 512 threads ----
#pragma unroll
    for (int rep = 0; rep < 2; ++rep) {
      int vidx = tid + rep * 512;           // 0..1023 -> t 0..127
      genv(vidx >> 3, vidx & 7);
    }
    if (tid < 16) genv(128 + (tid >> 3), tid & 7);  // t = 128,129
    __syncthreads();

    if (w < 4) {
      // ---- sim = q k^T (wave w owns rows [16w,16w+16)) ----
      f32x4 sacc[4] = {};
      {
        const unsigned short* qrow = &qb[(w * 16 + l15) * 168 + l4 * 8];
#pragma unroll
        for (int kk = 0; kk < 5; ++kk) {
          bf16x8 avv = *(const bf16x8*)&qrow[kk * 32];
#pragma unroll
          for (int cf = 0; cf < 4; ++cf) {
            bf16x8 bvv = *(const bf16x8*)&kb[(cf * 16 + l15) * 168 + l4 * 8 + kk * 32];
            sacc[cf] = __builtin_amdgcn_mfma_f32_16x16x32_bf16(avv, bvv, sacc[cf], 0, 0, 0);
          }
        }
      }
      // ---- in-register softmax over full rows ----
      float prob[4][4];
#pragma unroll
      for (int r = 0; r < 4; ++r) {
        float mx = fmaxf(fmaxf(sacc[0][r], sacc[1][r]), fmaxf(sacc[2][r], sacc[3][r]));
#pragma unroll
        for (int msk = 1; msk <= 8; msk <<= 1) mx = fmaxf(mx, __shfl_xor(mx, msk, 64));
        float ssum = 0.f;
#pragma unroll
        for (int cf = 0; cf < 4; ++cf) {
          float e = __expf((sacc[cf][r] - mx) * INVS);
          prob[cf][r] = e;
          ssum += e;
        }
#pragma unroll
        for (int msk = 1; msk <= 8; msk <<= 1) ssum += __shfl_xor(ssum, msk, 64);
        float is = 1.f / ssum;
#pragma unroll
        for (int cf = 0; cf < 4; ++cf) prob[cf][r] *= is;
      }
#pragma unroll
      for (int cf = 0; cf < 4; ++cf)
#pragma unroll
        for (int r = 0; r < 4; ++r)
          pb[(w * 16 + l4 * 4 + r) * 72 + cf * 16 + l15] = f2bf(prob[cf][r]);
      // pb rows produced and consumed by the same wave -> no barrier needed.

      // ---- ao = p v ----
      f32x4 aoacc[9] = {};
      {
        const unsigned short* prow = &pb[(w * 16 + l15) * 72 + l4 * 8];
#pragma unroll
        for (int kk = 0; kk < 2; ++kk) {
          bf16x8 avv = *(const bf16x8*)&prow[kk * 32];
#pragma unroll
          for (int sf = 0; sf < 9; ++sf) {
            bf16x8 bvv = *(const bf16x8*)&vT[(sf * 16 + l15) * 72 + l4 * 8 + kk * 32];
            aoacc[sf] = __builtin_amdgcn_mfma_f32_16x16x32_bf16(avv, bvv, aoacc[sf], 0, 0, 0);
          }
        }
      }
      // ---- fused Norm2 + Wlin projection via row statistics ----
      float csum = 0.f;
#pragma unroll
      for (int r = 0; r < 4; ++r) {
        int row = w * 16 + l4 * 4 + r;
        float s1 = 0.f, s2 = 0.f, sdt = 0.f;
#pragma unroll
        for (int sf = 0; sf < 9; ++sf) {
          int col = sf * 16 + l15;
          float v = aoacc[sf][r];
          if (col < 130) {
            s1 += v;
            s2 += v * v;
            sdt += v * AWw[row * 130 + col];
          }
        }
#pragma unroll
        for (int msk = 1; msk <= 8; msk <<= 1) {
          s1 += __shfl_xor(s1, msk, 64);
          s2 += __shfl_xor(s2, msk, 64);
          sdt += __shfl_xor(sdt, msk, 64);
        }
        float mz  = 2.f * s1 * (1.f / 130.f);
        float ez2 = 4.f * s2 * (1.f / 130.f);
        float sg  = sqrtf(fmaxf(ez2 - mz * mz, 0.f));
        float i2  = 1.f / (sg + EPSF);
        csum += (2.f * sdt - mz * Paw[row]) * i2;
      }
      float tsum = (l15 == 0) ? csum : 0.f;
#pragma unroll
      for (int msk = 1; msk <= 32; msk <<= 1) tsum += __shfl_xor(tsum, msk, 64);
      if (l == 0) redbuf[w] = tsum;
    }
    __syncthreads();
    if (tid == 0) out[b * 64 + n] = redbuf[0] + redbuf[1] + redbuf[2] + redbuf[3] + ccv;
  }
}

// ---------------- host launch ----------------
extern "C" void kernel_launch(void* const* d_in, const int* in_sizes, int n_in,
                              void* d_out, int out_size, void* d_ws, size_t ws_size,
                              hipStream_t stream) {
  const float* sp     = (const float*)d_in[0];
  const float* h1     = (const float*)d_in[1];
  const float* h2     = (const float*)d_in[2];
  const float* Wq     = (const float*)d_in[3];
  const float* bq     = (const float*)d_in[4];
  const float* Wk     = (const float*)d_in[5];
  const float* bk     = (const float*)d_in[6];
  const float* Wv     = (const float*)d_in[7];
  const float* bv     = (const float*)d_in[8];
  const float* alpha1 = (const float*)d_in[9];
  const float* beta1  = (const float*)d_in[10];
  const float* alpha2 = (const float*)d_in[11];
  const float* beta2  = (const float*)d_in[12];
  const float* Wlin   = (const float*)d_in[13];
  const float* blin   = (const float*)d_in[14];
  float* out = (float*)d_out;

  float* w   = (float*)d_ws;
  float* Uws = w;                    // 3*256*8320 = 6,389,760
  float* S1g = Uws + 6389760;        // 16384
  float* S2g = S1g + 16384;          // 16384
  float* Aws = S2g + 16384;          // 24960
  float* Bws = Aws + 24960;          // 24960
  float* AWw = Bws + 24960;          // 8320
  float* Paw = AWw + 8320;           // 64
  float* Ccw = Paw + 64;             // 1   -> total ~25.99 MB (same as R1)

  k0<<<dim3(7), dim3(256), 0, stream>>>(alpha1, beta1, alpha2, beta2,
                                        Wq, bq, Wk, bk, Wv, bv, Wlin, blin,
                                        Aws, Bws, AWw, Paw, Ccw);
  k1<<<dim3(256), dim3(256), 0, stream>>>(h1, h2, sp, alpha1, Wq, Wk, Wv,
                                          Uws, S1g, S2g);
  k2<<<dim3(2048), dim3(512), 0, stream>>>(h2, alpha1, Uws, Aws, Bws, S1g, S2g,
                                           AWw, Paw, Ccw, Wq, Wk, Wv, out);
}

// Round 3
// 1177.090 us; speedup vs baseline: 4.5971x; 1.2971x over previous
//
#include <hip/hip_runtime.h>
#include <math.h>

// ---------------------------------------------------------------------------
// AttnModel3: B=256, N=64, F=64, S=130.
//   q_f(n) = ( U_f + c_f(n)*W[129,:] - m_f(n)*A_f ) * inv_f(n) + B_f
// R3: all regen operands bf16, zero-padded to t=136, A/B interleaved per
// 8-group; per-XCD U footprint 1.67MB -> L2-resident with co-location.
// k2: grid 2048 = (8 n-tiles x 256 b), 512 thr.
// ---------------------------------------------------------------------------

typedef __attribute__((ext_vector_type(4))) float f32x4;
typedef __attribute__((ext_vector_type(8))) short bf16x8;

#define EPSF 1e-6f
#define INVS 0.0877058019307029f /* 1/sqrt(130) */

__device__ __forceinline__ unsigned short f2bf(float f) {
  unsigned int u = __builtin_bit_cast(unsigned int, f);
  u += 0x7FFFu + ((u >> 16) & 1u);
  return (unsigned short)(u >> 16);
}
__device__ __forceinline__ float b2f(short s) {
  unsigned int u = ((unsigned int)(unsigned short)s) << 16;
  return __builtin_bit_cast(float, u);
}

// ---------------- kernel 0: global precomputes (bf16 packed) ----------------
__global__ __launch_bounds__(256) void k0(
    const float* __restrict__ alpha1, const float* __restrict__ beta1,
    const float* __restrict__ alpha2, const float* __restrict__ beta2,
    const float* __restrict__ Wq, const float* __restrict__ bq,
    const float* __restrict__ Wk, const float* __restrict__ bk,
    const float* __restrict__ Wv, const float* __restrict__ bv,
    const float* __restrict__ Wlin, const float* __restrict__ blin,
    unsigned short* __restrict__ ABqk, unsigned short* __restrict__ ABv,
    float* __restrict__ AWw, float* __restrict__ Paw, float* __restrict__ Ccw)
{
  __shared__ float sbuf[64 * 132];
  __shared__ float Wbuf[130 * 144];
  int blk = blockIdx.x, tid = threadIdx.x;
  if (blk < 6) {
    int m = blk >> 1, isB = blk & 1;
    const float* src  = isB ? beta1 : alpha1;
    const float* W    = (m == 0) ? Wq : (m == 1) ? Wk : Wv;
    const float* bias = (m == 0) ? bq : (m == 1) ? bk : bv;
    for (int e = tid; e < 8320; e += 256) { int f = e / 130, s = e - f * 130; sbuf[f * 132 + s] = src[e]; }
    for (int e = tid; e < 16900; e += 256) { int s = e / 130, t = e - s * 130; Wbuf[s * 144 + t] = W[e]; }
    __syncthreads();
    int ty = tid >> 4, tx = tid & 15;
    float acc[4][9] = {};
    for (int s = 0; s < 130; ++s) {
      float g0 = sbuf[(ty * 4 + 0) * 132 + s];
      float g1 = sbuf[(ty * 4 + 1) * 132 + s];
      float g2 = sbuf[(ty * 4 + 2) * 132 + s];
      float g3 = sbuf[(ty * 4 + 3) * 132 + s];
#pragma unroll
      for (int c = 0; c < 9; ++c) {
        float wv = Wbuf[s * 144 + tx + 16 * c];
        acc[0][c] += g0 * wv; acc[1][c] += g1 * wv;
        acc[2][c] += g2 * wv; acc[3][c] += g3 * wv;
      }
    }
#pragma unroll
    for (int i = 0; i < 4; ++i)
      for (int c = 0; c < 9; ++c) {
        int t = tx + 16 * c;
        if (t < 136) {
          float val = (t < 130) ? (acc[i][c] + (isB ? bias[t] : 0.f)) : 0.f;
          unsigned short v16 = f2bf(val);
          int f = ty * 4 + i;
          if (m == 2) ABv[t * 128 + isB * 64 + f] = v16;                       // [t][{A,B}][f]
          else        ABqk[(m * 64 + f) * 272 + (t >> 3) * 16 + isB * 8 + (t & 7)] = v16;
        }
      }
  } else if (blk == 6) {
    if (tid < 64) {
      int f = tid;
      float pa = 0.f, cc = 0.f;
      for (int s = 0; s < 130; ++s) {
        float wl = Wlin[f * 130 + s];
        float aw = alpha2[f * 130 + s] * wl;
        AWw[f * 130 + s] = aw;
        pa += aw;
        cc += beta2[f * 130 + s] * wl;
      }
      Paw[f] = pa;
#pragma unroll
      for (int msk = 1; msk <= 32; msk <<= 1) cc += __shfl_xor(cc, msk, 64);
      if (f == 0) Ccw[0] = cc + blin[0];
    }
  }
}

// ---------------- kernel 1: per-b U (bf16), S1, S2 ----------------
__global__ __launch_bounds__(256) void k1(
    const float* __restrict__ h1, const float* __restrict__ h2,
    const float* __restrict__ sp, const float* __restrict__ alpha1,
    const float* __restrict__ Wq, const float* __restrict__ Wk, const float* __restrict__ Wv,
    unsigned short* __restrict__ UqkB, unsigned short* __restrict__ UvB,
    float* __restrict__ S1g, float* __restrict__ S2g)
{
  __shared__ float gbuf[64 * 132];
  __shared__ float Wbuf[130 * 144];
  __shared__ float ps[2][256];
  int b = blockIdx.x, tid = threadIdx.x;
  float s1 = 0.f, s2 = 0.f;
  for (int idx = tid; idx < 8256; idx += 256) {  // 129*64
    int s = idx >> 6, f = idx & 63;
    float x = (s < 64)  ? h1[((size_t)(b * 64 + s)) * 64 + f]
            : (s < 128) ? h2[((size_t)(b * 64 + (s - 64))) * 64 + f]
                        : sp[b * 64 + f];
    gbuf[f * 132 + s] = alpha1[f * 130 + s] * x;
    s1 += x; s2 += x * x;
  }
  ps[0][tid] = s1; ps[1][tid] = s2;
  __syncthreads();
  if (tid < 64) {
    S1g[b * 64 + tid] = ps[0][tid] + ps[0][tid + 64] + ps[0][tid + 128] + ps[0][tid + 192];
    S2g[b * 64 + tid] = ps[1][tid] + ps[1][tid + 64] + ps[1][tid + 128] + ps[1][tid + 192];
  }
  int ty = tid >> 4, tx = tid & 15;
  for (int m = 0; m < 3; ++m) {
    const float* W = (m == 0) ? Wq : (m == 1) ? Wk : Wv;
    __syncthreads();
    for (int e = tid; e < 16900; e += 256) { int s = e / 130, t = e - s * 130; Wbuf[s * 144 + t] = W[e]; }
    __syncthreads();
    float acc[4][9] = {};
    for (int s = 0; s < 129; ++s) {  // K = 129 (col 129 handled per-n)
      float g0 = gbuf[(ty * 4 + 0) * 132 + s];
      float g1 = gbuf[(ty * 4 + 1) * 132 + s];
      float g2 = gbuf[(ty * 4 + 2) * 132 + s];
      float g3 = gbuf[(ty * 4 + 3) * 132 + s];
#pragma unroll
      for (int c = 0; c < 9; ++c) {
        float wv = Wbuf[s * 144 + tx + 16 * c];
        acc[0][c] += g0 * wv; acc[1][c] += g1 * wv;
        acc[2][c] += g2 * wv; acc[3][c] += g3 * wv;
      }
    }
#pragma unroll
    for (int i = 0; i < 4; ++i)
      for (int c = 0; c < 9; ++c) {
        int t = tx + 16 * c;
        if (t < 136) {
          unsigned short v16 = f2bf((t < 130) ? acc[i][c] : 0.f);
          int f = ty * 4 + i;
          if (m == 2) UvB[((size_t)b * 136 + t) * 64 + f] = v16;               // [t][f]
          else        UqkB[(((size_t)b * 2 + m) * 64 + f) * 136 + t] = v16;    // [f][t]
        }
      }
  }
}

// ---------------- kernel 2: per-(b, n-tile) attention ----------------
__global__ __launch_bounds__(512, 4) void k2(
    const float* __restrict__ h2, const float* __restrict__ alpha1,
    const unsigned short* __restrict__ UqkB, const unsigned short* __restrict__ UvB,
    const unsigned short* __restrict__ ABqk, const unsigned short* __restrict__ ABv,
    const float* __restrict__ S1g, const float* __restrict__ S2g,
    const float* __restrict__ AWw, const float* __restrict__ Paw, const float* __restrict__ Ccw,
    const float* __restrict__ Wq, const float* __restrict__ Wk, const float* __restrict__ Wv,
    float* __restrict__ out)
{
  __shared__ __align__(16) unsigned short qb[64 * 168];  // rows f, cols t (K-pad to 160)
  __shared__ __align__(16) unsigned short kb[64 * 168];
  __shared__ __align__(16) unsigned short vT[144 * 72];  // rows s(144), cols j(64)
  __shared__ __align__(16) unsigned short pb[64 * 72];
  __shared__ __align__(16) float w129l[3][136];
  __shared__ __align__(16) float S1l[64], S2l[64], ael[64];
  __shared__ __align__(16) float mrow[64], irow[64], crow[64];
  __shared__ float redbuf[4];

  // XCD co-location: all 8 n-tile blocks of a given b land on the same XCD.
  int flat = blockIdx.x;
  int xcd = flat & 7, jj = flat >> 3;
  int b  = ((jj >> 3) << 3) + xcd;
  int n0 = (jj & 7) * 8;

  int tid = threadIdx.x;
  int w = tid >> 6, l = tid & 63, l15 = l & 15, l4 = l >> 4;

  if (tid < 136) {
    w129l[0][tid] = (tid < 130) ? Wq[129 * 130 + tid] : 0.f;
    w129l[1][tid] = (tid < 130) ? Wk[129 * 130 + tid] : 0.f;
    w129l[2][tid] = (tid < 130) ? Wv[129 * 130 + tid] : 0.f;
  }
  if (tid >= 256 && tid < 320) {
    int f = tid - 256;
    S1l[f] = S1g[b * 64 + f];
    S2l[f] = S2g[b * 64 + f];
    ael[f] = alpha1[f * 130 + 129];
  }
  // zero MFMA K-tails [136,160) once; regen rewrites only [0,136)
  for (int i = tid; i < 64 * 24; i += 512) {
    int f = i / 24, t = 136 + (i - f * 24);
    qb[f * 168 + t] = 0; kb[f * 168 + t] = 0;
  }
  for (int i = tid; i < 14 * 72; i += 512) vT[130 * 72 + i] = 0;  // zero pad rows
  float ccv = Ccw[0];
  __syncthreads();

  const unsigned short* uqk = UqkB + ((size_t)b * 2) * 64 * 136;
  const unsigned short* uvb = UvB + (size_t)b * 136 * 64;

  auto genv = [&](int t, int f8) {
    float wv = w129l[2][t];
    bf16x8 uu = *(const bf16x8*)(uvb + t * 64 + f8 * 8);
    bf16x8 aa = *(const bf16x8*)(ABv + t * 128 + f8 * 8);
    bf16x8 bb = *(const bf16x8*)(ABv + t * 128 + 64 + f8 * 8);
    f32x4 m0 = *(const f32x4*)&mrow[f8 * 8], m1 = *(const f32x4*)&mrow[f8 * 8 + 4];
    f32x4 i0 = *(const f32x4*)&irow[f8 * 8], i1 = *(const f32x4*)&irow[f8 * 8 + 4];
    f32x4 c0 = *(const f32x4*)&crow[f8 * 8], c1 = *(const f32x4*)&crow[f8 * 8 + 4];
    bf16x8 vv;
#pragma unroll
    for (int e = 0; e < 4; ++e)
      vv[e] = (short)f2bf((b2f(uu[e]) + c0[e] * wv - m0[e] * b2f(aa[e])) * i0[e] + b2f(bb[e]));
#pragma unroll
    for (int e = 0; e < 4; ++e)
      vv[4 + e] = (short)f2bf((b2f(uu[4 + e]) + c1[e] * wv - m1[e] * b2f(aa[4 + e])) * i1[e] + b2f(bb[4 + e]));
    *(bf16x8*)&vT[t * 72 + f8 * 8] = vv;
  };

  for (int ni = 0; ni < 8; ++ni) {
    int n = n0 + ni;
    if (tid < 64) {
      float a  = h2[((size_t)(b * 64 + n)) * 64 + tid];
      float m  = (S1l[tid] + a) * (1.f / 130.f);
      float e2 = (S2l[tid] + a * a) * (1.f / 130.f);
      float sd = sqrtf(fmaxf(e2 - m * m, 0.f));
      mrow[tid] = m;
      irow[tid] = 1.f / (sd + EPSF);
      crow[tid] = ael[tid] * a;
    }
    __syncthreads();

    // ---- generate q (tid<256) / k (tid>=256): 4 groups/thread + tail ----
    {
      int isK = tid >> 8;
      int t5 = tid & 255;
      int f = t5 >> 2, c3 = t5 & 3;
      float m = mrow[f], inv = irow[f], c = crow[f];
      const unsigned short* ub = uqk + (isK * 64 + f) * 136;
      const unsigned short* ab = ABqk + (isK * 64 + f) * 272;
      const float* wl = w129l[isK];
      unsigned short* dst = (isK ? kb : qb) + f * 168;
#pragma unroll
      for (int kgrp = 0; kgrp < 4; ++kgrp) {
        int g = c3 + kgrp * 4;
        bf16x8 uu = *(const bf16x8*)(ub + g * 8);
        bf16x8 aa = *(const bf16x8*)(ab + g * 16);
        bf16x8 bb = *(const bf16x8*)(ab + g * 16 + 8);
        bf16x8 ov;
#pragma unroll
        for (int e = 0; e < 8; ++e) {
          int t = g * 8 + e;
          ov[e] = (short)f2bf((b2f(uu[e]) + c * wl[t] - m * b2f(aa[e])) * inv + b2f(bb[e]));
        }
        *(bf16x8*)(dst + g * 8) = ov;
      }
      if (t5 < 64) {  // group 16 (t=128..135; 130+ are zero operands)
        int f2 = t5;
        float m2 = mrow[f2], inv2 = irow[f2], c2 = crow[f2];
        const unsigned short* ub2 = uqk + (isK * 64 + f2) * 136 + 128;
        const unsigned short* ab2 = ABqk + (isK * 64 + f2) * 272 + 256;
        bf16x8 uu = *(const bf16x8*)(ub2);
        bf16x8 aa = *(const bf16x8*)(ab2);
        bf16x8 bb = *(const bf16x8*)(ab2 + 8);
        bf16x8 ov;
#pragma unroll
        for (int e = 0; e < 8; ++e) {
          ov[e] = (short)f2bf((b2f(uu[e]) + c2 * wl[128 + e] - m2 * b2f(aa[e])) * inv2 + b2f(bb[e]));
        }
        *(bf16x8*)((isK ? kb : qb) + f2 * 168 + 128) = ov;
      }
    }
    // ---- generate v^T ----
#pragma unroll
    for (int rep = 0; rep < 2; ++rep) {
      int vidx = tid + rep * 512;           // 0..1023 -> t 0..127
      genv(vidx >> 3, vidx & 7);
    }
    if (tid < 16) genv(128 + (tid >> 3), tid & 7);  // t = 128,129
    __syncthreads();

    if (w < 4) {
      // ---- sim = q k^T (wave w owns rows [16w,16w+16)) ----
      f32x4 sacc[4] = {};
      {
        const unsigned short* qrow = &qb[(w * 16 + l15) * 168 + l4 * 8];
#pragma unroll
        for (int kk = 0; kk < 5; ++kk) {
          bf16x8 avv = *(const bf16x8*)&qrow[kk * 32];
#pragma unroll
          for (int cf = 0; cf < 4; ++cf) {
            bf16x8 bvv = *(const bf16x8*)&kb[(cf * 16 + l15) * 168 + l4 * 8 + kk * 32];
            sacc[cf] = __builtin_amdgcn_mfma_f32_16x16x32_bf16(avv, bvv, sacc[cf], 0, 0, 0);
          }
        }
      }
      // ---- in-register softmax over full rows ----
      float prob[4][4];
#pragma unroll
      for (int r = 0; r < 4; ++r) {
        float mx = fmaxf(fmaxf(sacc[0][r], sacc[1][r]), fmaxf(sacc[2][r], sacc[3][r]));
#pragma unroll
        for (int msk = 1; msk <= 8; msk <<= 1) mx = fmaxf(mx, __shfl_xor(mx, msk, 64));
        float ssum = 0.f;
#pragma unroll
        for (int cf = 0; cf < 4; ++cf) {
          float e = __expf((sacc[cf][r] - mx) * INVS);
          prob[cf][r] = e;
          ssum += e;
        }
#pragma unroll
        for (int msk = 1; msk <= 8; msk <<= 1) ssum += __shfl_xor(ssum, msk, 64);
        float is = 1.f / ssum;
#pragma unroll
        for (int cf = 0; cf < 4; ++cf) prob[cf][r] *= is;
      }
#pragma unroll
      for (int cf = 0; cf < 4; ++cf)
#pragma unroll
        for (int r = 0; r < 4; ++r)
          pb[(w * 16 + l4 * 4 + r) * 72 + cf * 16 + l15] = f2bf(prob[cf][r]);
      // pb rows produced and consumed by the same wave -> no barrier needed.

      // ---- ao = p v ----
      f32x4 aoacc[9] = {};
      {
        const unsigned short* prow = &pb[(w * 16 + l15) * 72 + l4 * 8];
#pragma unroll
        for (int kk = 0; kk < 2; ++kk) {
          bf16x8 avv = *(const bf16x8*)&prow[kk * 32];
#pragma unroll
          for (int sf = 0; sf < 9; ++sf) {
            bf16x8 bvv = *(const bf16x8*)&vT[(sf * 16 + l15) * 72 + l4 * 8 + kk * 32];
            aoacc[sf] = __builtin_amdgcn_mfma_f32_16x16x32_bf16(avv, bvv, aoacc[sf], 0, 0, 0);
          }
        }
      }
      // ---- fused Norm2 + Wlin projection via row statistics ----
      float csum = 0.f;
#pragma unroll
      for (int r = 0; r < 4; ++r) {
        int row = w * 16 + l4 * 4 + r;
        float s1 = 0.f, s2 = 0.f, sdt = 0.f;
#pragma unroll
        for (int sf = 0; sf < 9; ++sf) {
          int col = sf * 16 + l15;
          float v = aoacc[sf][r];
          if (col < 130) {
            s1 += v;
            s2 += v * v;
            sdt += v * AWw[row * 130 + col];
          }
        }
#pragma unroll
        for (int msk = 1; msk <= 8; msk <<= 1) {
          s1 += __shfl_xor(s1, msk, 64);
          s2 += __shfl_xor(s2, msk, 64);
          sdt += __shfl_xor(sdt, msk, 64);
        }
        float mz  = 2.f * s1 * (1.f / 130.f);
        float ez2 = 4.f * s2 * (1.f / 130.f);
        float sg  = sqrtf(fmaxf(ez2 - mz * mz, 0.f));
        float i2  = 1.f / (sg + EPSF);
        csum += (2.f * sdt - mz * Paw[row]) * i2;
      }
      float tsum = (l15 == 0) ? csum : 0.f;
#pragma unroll
      for (int msk = 1; msk <= 32; msk <<= 1) tsum += __shfl_xor(tsum, msk, 64);
      if (l == 0) redbuf[w] = tsum;
    }
    __syncthreads();
    if (tid == 0) out[b * 64 + n] = redbuf[0] + redbuf[1] + redbuf[2] + redbuf[3] + ccv;
  }
}

// ---------------- host launch ----------------
extern "C" void kernel_launch(void* const* d_in, const int* in_sizes, int n_in,
                              void* d_out, int out_size, void* d_ws, size_t ws_size,
                              hipStream_t stream) {
  const float* sp     = (const float*)d_in[0];
  const float* h1     = (const float*)d_in[1];
  const float* h2     = (const float*)d_in[2];
  const float* Wq     = (const float*)d_in[3];
  const float* bq     = (const float*)d_in[4];
  const float* Wk     = (const float*)d_in[5];
  const float* bk     = (const float*)d_in[6];
  const float* Wv     = (const float*)d_in[7];
  const float* bv     = (const float*)d_in[8];
  const float* alpha1 = (const float*)d_in[9];
  const float* beta1  = (const float*)d_in[10];
  const float* alpha2 = (const float*)d_in[11];
  const float* beta2  = (const float*)d_in[12];
  const float* Wlin   = (const float*)d_in[13];
  const float* blin   = (const float*)d_in[14];
  float* out = (float*)d_out;

  unsigned short* UqkB = (unsigned short*)d_ws;     // 256*2*64*136 = 4,456,448
  unsigned short* UvB  = UqkB + 4456448;            // 256*136*64   = 2,228,224
  unsigned short* ABqk = UvB + 2228224;             // 2*64*272     = 34,816
  unsigned short* ABv  = ABqk + 34816;              // 136*128      = 17,408
  float* S1g = (float*)(ABv + 17408);               // 16384
  float* S2g = S1g + 16384;                         // 16384
  float* AWw = S2g + 16384;                         // 8320
  float* Paw = AWw + 8320;                          // 64
  float* Ccw = Paw + 64;                            // 1   -> total ~13.6 MB

  k0<<<dim3(7), dim3(256), 0, stream>>>(alpha1, beta1, alpha2, beta2,
                                        Wq, bq, Wk, bk, Wv, bv, Wlin, blin,
                                        ABqk, ABv, AWw, Paw, Ccw);
  k1<<<dim3(256), dim3(256), 0, stream>>>(h1, h2, sp, alpha1, Wq, Wk, Wv,
                                          UqkB, UvB, S1g, S2g);
  k2<<<dim3(2048), dim3(512), 0, stream>>>(h2, alpha1, UqkB, UvB, ABqk, ABv,
                                           S1g, S2g, AWw, Paw, Ccw,
                                           Wq, Wk, Wv, out);
}

// Round 5
// 459.885 us; speedup vs baseline: 11.7665x; 2.5595x over previous
//
#include <hip/hip_runtime.h>
#include <math.h>

// ---------------------------------------------------------------------------
// AttnModel3: B=256, N=64, F=64, S=130.
//   q_f(n) = ( U_f + c_f(n)*W[129,:] - m_f(n)*A_f ) * inv_f(n) + B_f
// R5 = R4 with two fixes:
//   (1) uv_l staging covered only cols 0..31 (i<136*4, c=i&3) -> NaN from
//       uninitialized LDS. Now 1088 chunks, t=i>>3, c=i&7.
//   (2) PV loop had runtime trip count (scratch risk + vT OOB for half=1);
//       now wave-uniform compile-time-unrolled branches.
// Per-b U + AW staged in LDS once per block (grid 256, 1 block/b, 64 n).
// Per-n global traffic = shared A/B tables only (~105 KB, L2-resident).
// ---------------------------------------------------------------------------

typedef __attribute__((ext_vector_type(4))) float f32x4;
typedef __attribute__((ext_vector_type(8))) short bf16x8;

#define EPSF 1e-6f
#define INVS 0.0877058019307029f /* 1/sqrt(130) */

__device__ __forceinline__ unsigned short f2bf(float f) {
  unsigned int u = __builtin_bit_cast(unsigned int, f);
  u += 0x7FFFu + ((u >> 16) & 1u);
  return (unsigned short)(u >> 16);
}
__device__ __forceinline__ float b2f(unsigned short s) {
  unsigned int u = ((unsigned int)s) << 16;
  return __builtin_bit_cast(float, u);
}

// ---------------- kernel 0: global precomputes (bf16 packed) ----------------
__global__ __launch_bounds__(256) void k0(
    const float* __restrict__ alpha1, const float* __restrict__ beta1,
    const float* __restrict__ alpha2, const float* __restrict__ beta2,
    const float* __restrict__ Wq, const float* __restrict__ bq,
    const float* __restrict__ Wk, const float* __restrict__ bk,
    const float* __restrict__ Wv, const float* __restrict__ bv,
    const float* __restrict__ Wlin, const float* __restrict__ blin,
    unsigned short* __restrict__ ABqk, unsigned short* __restrict__ ABv,
    unsigned short* __restrict__ AWb, float* __restrict__ Paw, float* __restrict__ Ccw)
{
  __shared__ float sbuf[64 * 132];
  __shared__ float Wbuf[130 * 144];
  int blk = blockIdx.x, tid = threadIdx.x;
  if (blk < 6) {
    int m = blk >> 1, isB = blk & 1;
    const float* src  = isB ? beta1 : alpha1;
    const float* W    = (m == 0) ? Wq : (m == 1) ? Wk : Wv;
    const float* bias = (m == 0) ? bq : (m == 1) ? bk : bv;
    for (int e = tid; e < 8320; e += 256) { int f = e / 130, s = e - f * 130; sbuf[f * 132 + s] = src[e]; }
    for (int e = tid; e < 16900; e += 256) { int s = e / 130, t = e - s * 130; Wbuf[s * 144 + t] = W[e]; }
    __syncthreads();
    int ty = tid >> 4, tx = tid & 15;
    float acc[4][9] = {};
    for (int s = 0; s < 130; ++s) {
      float g0 = sbuf[(ty * 4 + 0) * 132 + s];
      float g1 = sbuf[(ty * 4 + 1) * 132 + s];
      float g2 = sbuf[(ty * 4 + 2) * 132 + s];
      float g3 = sbuf[(ty * 4 + 3) * 132 + s];
#pragma unroll
      for (int c = 0; c < 9; ++c) {
        float wv = Wbuf[s * 144 + tx + 16 * c];
        acc[0][c] += g0 * wv; acc[1][c] += g1 * wv;
        acc[2][c] += g2 * wv; acc[3][c] += g3 * wv;
      }
    }
#pragma unroll
    for (int i = 0; i < 4; ++i)
      for (int c = 0; c < 9; ++c) {
        int t = tx + 16 * c;
        if (t < 136) {
          float val = (t < 130) ? (acc[i][c] + (isB ? bias[t] : 0.f)) : 0.f;
          unsigned short v16 = f2bf(val);
          int f = ty * 4 + i;
          if (m == 2) ABv[t * 128 + isB * 64 + f] = v16;                       // [t][{A,B}][f]
          else        ABqk[(m * 64 + f) * 272 + (t >> 3) * 16 + isB * 8 + (t & 7)] = v16;
        }
      }
  } else if (blk == 6) {
    if (tid < 64) {
      int f = tid;
      float pa = 0.f, cc = 0.f;
      for (int s = 0; s < 130; ++s) {
        float wl = Wlin[f * 130 + s];
        float aw = alpha2[f * 130 + s] * wl;
        AWb[f * 136 + s] = f2bf(aw);
        pa += aw;
        cc += beta2[f * 130 + s] * wl;
      }
#pragma unroll
      for (int s = 130; s < 136; ++s) AWb[f * 136 + s] = 0;
      Paw[f] = pa;
#pragma unroll
      for (int msk = 1; msk <= 32; msk <<= 1) cc += __shfl_xor(cc, msk, 64);
      if (f == 0) Ccw[0] = cc + blin[0];
    }
  }
}

// ---------------- kernel 1: per-b U (bf16), S1, S2 ----------------
__global__ __launch_bounds__(256) void k1(
    const float* __restrict__ h1, const float* __restrict__ h2,
    const float* __restrict__ sp, const float* __restrict__ alpha1,
    const float* __restrict__ Wq, const float* __restrict__ Wk, const float* __restrict__ Wv,
    unsigned short* __restrict__ UqkB, unsigned short* __restrict__ UvB,
    float* __restrict__ S1g, float* __restrict__ S2g)
{
  __shared__ float gbuf[64 * 132];
  __shared__ float Wbuf[130 * 144];
  __shared__ float ps[2][256];
  int b = blockIdx.x, tid = threadIdx.x;
  float s1 = 0.f, s2 = 0.f;
  for (int idx = tid; idx < 8256; idx += 256) {  // 129*64
    int s = idx >> 6, f = idx & 63;
    float x = (s < 64)  ? h1[((size_t)(b * 64 + s)) * 64 + f]
            : (s < 128) ? h2[((size_t)(b * 64 + (s - 64))) * 64 + f]
                        : sp[b * 64 + f];
    gbuf[f * 132 + s] = alpha1[f * 130 + s] * x;
    s1 += x; s2 += x * x;
  }
  ps[0][tid] = s1; ps[1][tid] = s2;
  __syncthreads();
  if (tid < 64) {
    S1g[b * 64 + tid] = ps[0][tid] + ps[0][tid + 64] + ps[0][tid + 128] + ps[0][tid + 192];
    S2g[b * 64 + tid] = ps[1][tid] + ps[1][tid + 64] + ps[1][tid + 128] + ps[1][tid + 192];
  }
  int ty = tid >> 4, tx = tid & 15;
  for (int m = 0; m < 3; ++m) {
    const float* W = (m == 0) ? Wq : (m == 1) ? Wk : Wv;
    __syncthreads();
    for (int e = tid; e < 16900; e += 256) { int s = e / 130, t = e - s * 130; Wbuf[s * 144 + t] = W[e]; }
    __syncthreads();
    float acc[4][9] = {};
    for (int s = 0; s < 129; ++s) {  // K = 129 (col 129 handled per-n)
      float g0 = gbuf[(ty * 4 + 0) * 132 + s];
      float g1 = gbuf[(ty * 4 + 1) * 132 + s];
      float g2 = gbuf[(ty * 4 + 2) * 132 + s];
      float g3 = gbuf[(ty * 4 + 3) * 132 + s];
#pragma unroll
      for (int c = 0; c < 9; ++c) {
        float wv = Wbuf[s * 144 + tx + 16 * c];
        acc[0][c] += g0 * wv; acc[1][c] += g1 * wv;
        acc[2][c] += g2 * wv; acc[3][c] += g3 * wv;
      }
    }
#pragma unroll
    for (int i = 0; i < 4; ++i)
      for (int c = 0; c < 9; ++c) {
        int t = tx + 16 * c;
        if (t < 136) {
          unsigned short v16 = f2bf((t < 130) ? acc[i][c] : 0.f);
          int f = ty * 4 + i;
          if (m == 2) UvB[((size_t)b * 136 + t) * 64 + f] = v16;               // [t][f]
          else        UqkB[(((size_t)b * 2 + m) * 64 + f) * 136 + t] = v16;    // [f][t]
        }
      }
  }
}

// ---------------- kernel 2: per-b attention, all 64 n ----------------
__global__ __launch_bounds__(512, 1) void k2(
    const float* __restrict__ h2, const float* __restrict__ alpha1,
    const unsigned short* __restrict__ UqkB, const unsigned short* __restrict__ UvB,
    const unsigned short* __restrict__ ABqk, const unsigned short* __restrict__ ABv,
    const unsigned short* __restrict__ AWb,
    const float* __restrict__ S1g, const float* __restrict__ S2g,
    const float* __restrict__ Paw, const float* __restrict__ Ccw,
    const float* __restrict__ Wq, const float* __restrict__ Wk, const float* __restrict__ Wv,
    float* __restrict__ out)
{
  __shared__ __align__(16) unsigned short qb[64 * 168];     // 21504 B
  __shared__ __align__(16) unsigned short kb[64 * 168];     // 21504 B
  __shared__ __align__(16) unsigned short vT[144 * 72];     // 20736 B
  __shared__ __align__(16) unsigned short pb[64 * 72];      //  9216 B
  __shared__ __align__(16) unsigned short uqk_l[2 * 64 * 136]; // 34816 B
  __shared__ __align__(16) unsigned short uv_l[136 * 72];   // 19584 B
  __shared__ __align__(16) unsigned short AW_l[64 * 136];   // 17408 B
  __shared__ __align__(16) float w129l[3][136];
  __shared__ float S1l[64], S2l[64], ael[64];
  __shared__ float mrow[64], irow[64], crow[64];
  __shared__ float smaxl[8][16];
  __shared__ float ssuml[8][16];
  __shared__ float stred[8][16][4];

  int b = blockIdx.x;
  int tid = threadIdx.x;
  int w = tid >> 6, l = tid & 63, l15 = l & 15, l4 = l >> 4;
  int band = w >> 1, half = w & 1;

  // ---- one-time block setup ----
  if (tid < 136) {
    w129l[0][tid] = (tid < 130) ? Wq[129 * 130 + tid] : 0.f;
    w129l[1][tid] = (tid < 130) ? Wk[129 * 130 + tid] : 0.f;
    w129l[2][tid] = (tid < 130) ? Wv[129 * 130 + tid] : 0.f;
  }
  if (tid >= 256 && tid < 320) {
    int f = tid - 256;
    S1l[f] = S1g[b * 64 + f];
    S2l[f] = S2g[b * 64 + f];
    ael[f] = alpha1[f * 130 + 129];
  }
  // stage per-b U (q/k): 34816 B = 2176 x 16B
  {
    const uint4* src = (const uint4*)(UqkB + ((size_t)b * 2) * 64 * 136);
    uint4* dst = (uint4*)uqk_l;
    for (int i = tid; i < 2176; i += 512) dst[i] = src[i];
  }
  // stage per-b U (v): [136][64] -> [136][72]  (FIX: 8 chunks per row, not 4)
  {
    const unsigned short* src = UvB + (size_t)b * 136 * 64;
    for (int i = tid; i < 136 * 8; i += 512) {
      int t = i >> 3, c = i & 7;
      *(uint4*)&uv_l[t * 72 + c * 8] = *(const uint4*)&src[t * 64 + c * 8];
    }
  }
  // stage AW (bf16, padded layout)
  {
    const uint4* src = (const uint4*)AWb;
    uint4* dst = (uint4*)AW_l;
    for (int i = tid; i < 1088; i += 512) dst[i] = src[i];
  }
  // zero MFMA K-tails [136,160) once; regen rewrites only [0,136)
  for (int i = tid; i < 64 * 24; i += 512) {
    int f = i / 24, t = 136 + (i - f * 24);
    qb[f * 168 + t] = 0; kb[f * 168 + t] = 0;
  }
  for (int i = tid; i < 14 * 72; i += 512) vT[130 * 72 + i] = 0;  // zero pad rows
  float ccv = Ccw[0];
  __syncthreads();

  auto genv = [&](int t, int f8) {
    float wv = w129l[2][t];
    bf16x8 uu = *(const bf16x8*)(uv_l + t * 72 + f8 * 8);
    bf16x8 aa = *(const bf16x8*)(ABv + t * 128 + f8 * 8);
    bf16x8 bb = *(const bf16x8*)(ABv + t * 128 + 64 + f8 * 8);
    f32x4 m0 = *(const f32x4*)&mrow[f8 * 8], m1 = *(const f32x4*)&mrow[f8 * 8 + 4];
    f32x4 i0 = *(const f32x4*)&irow[f8 * 8], i1 = *(const f32x4*)&irow[f8 * 8 + 4];
    f32x4 c0 = *(const f32x4*)&crow[f8 * 8], c1 = *(const f32x4*)&crow[f8 * 8 + 4];
    bf16x8 vv;
#pragma unroll
    for (int e = 0; e < 4; ++e)
      vv[e] = (short)f2bf((b2f(uu[e]) + c0[e] * wv - m0[e] * b2f(aa[e])) * i0[e] + b2f(bb[e]));
#pragma unroll
    for (int e = 0; e < 4; ++e)
      vv[4 + e] = (short)f2bf((b2f(uu[4 + e]) + c1[e] * wv - m1[e] * b2f(aa[4 + e])) * i1[e] + b2f(bb[4 + e]));
    *(bf16x8*)&vT[t * 72 + f8 * 8] = vv;
  };

  for (int n = 0; n < 64; ++n) {
    // ---- per-n coefficients ----
    if (tid < 64) {
      float a  = h2[((size_t)(b * 64 + n)) * 64 + tid];
      float m  = (S1l[tid] + a) * (1.f / 130.f);
      float e2 = (S2l[tid] + a * a) * (1.f / 130.f);
      float sd = sqrtf(fmaxf(e2 - m * m, 0.f));
      mrow[tid] = m;
      irow[tid] = 1.f / (sd + EPSF);
      crow[tid] = ael[tid] * a;
    }
    __syncthreads();

    // ---- regen q (tid<256) / k (tid>=256): U from LDS, A/B from global ----
    {
      int isK = tid >> 8;
      int t5 = tid & 255;
      int f = t5 >> 2, c3 = t5 & 3;
      float m = mrow[f], inv = irow[f], c = crow[f];
      const unsigned short* ub = uqk_l + (isK * 64 + f) * 136;
      const unsigned short* ab = ABqk + (isK * 64 + f) * 272;
      const float* wl = w129l[isK];
      unsigned short* dst = (isK ? kb : qb) + f * 168;
#pragma unroll
      for (int kgrp = 0; kgrp < 4; ++kgrp) {
        int g = c3 + kgrp * 4;
        bf16x8 uu = *(const bf16x8*)(ub + g * 8);
        bf16x8 aa = *(const bf16x8*)(ab + g * 16);
        bf16x8 bb = *(const bf16x8*)(ab + g * 16 + 8);
        bf16x8 ov;
#pragma unroll
        for (int e = 0; e < 8; ++e) {
          int t = g * 8 + e;
          ov[e] = (short)f2bf((b2f(uu[e]) + c * wl[t] - m * b2f(aa[e])) * inv + b2f(bb[e]));
        }
        *(bf16x8*)(dst + g * 8) = ov;
      }
      if (t5 < 64) {  // tail: t = 128..135 (t>=130 operands are zero)
        int f2 = t5;
        float m2 = mrow[f2], inv2 = irow[f2], c2 = crow[f2];
        const unsigned short* ub2 = uqk_l + (isK * 64 + f2) * 136 + 128;
        const unsigned short* ab2 = ABqk + (isK * 64 + f2) * 272 + 256;
        bf16x8 uu = *(const bf16x8*)(ub2);
        bf16x8 aa = *(const bf16x8*)(ab2);
        bf16x8 bb = *(const bf16x8*)(ab2 + 8);
        bf16x8 ov;
#pragma unroll
        for (int e = 0; e < 8; ++e)
          ov[e] = (short)f2bf((b2f(uu[e]) + c2 * wl[128 + e] - m2 * b2f(aa[e])) * inv2 + b2f(bb[e]));
        *(bf16x8*)((isK ? kb : qb) + f2 * 168 + 128) = ov;
      }
    }
    // ---- regen v^T ----
#pragma unroll
    for (int rep = 0; rep < 2; ++rep) {
      int vidx = tid + rep * 512;           // 0..1023 -> t 0..127
      genv(vidx >> 3, vidx & 7);
    }
    if (tid < 16) genv(128 + (tid >> 3), tid & 7);  // t = 128,129
    __syncthreads();

    // ---- sim = q k^T: wave (band, half) -> rows band*16.., cols half*32.. ----
    f32x4 sacc[2] = {};
    {
      const unsigned short* qrow = &qb[(band * 16 + l15) * 168 + l4 * 8];
#pragma unroll
      for (int kk = 0; kk < 5; ++kk) {
        bf16x8 avv = *(const bf16x8*)&qrow[kk * 32];
#pragma unroll
        for (int cf2 = 0; cf2 < 2; ++cf2) {
          int cf = half * 2 + cf2;
          bf16x8 bvv = *(const bf16x8*)&kb[(cf * 16 + l15) * 168 + l4 * 8 + kk * 32];
          sacc[cf2] = __builtin_amdgcn_mfma_f32_16x16x32_bf16(avv, bvv, sacc[cf2], 0, 0, 0);
        }
      }
    }
    // ---- softmax: paired cross-wave (two col-halves) via LDS ----
    float pmax[4];
#pragma unroll
    for (int r = 0; r < 4; ++r) {
      float mx = fmaxf(sacc[0][r], sacc[1][r]);
#pragma unroll
      for (int msk = 1; msk <= 8; msk <<= 1) mx = fmaxf(mx, __shfl_xor(mx, msk, 64));
      pmax[r] = mx;
    }
    if (l15 == 0) {
#pragma unroll
      for (int r = 0; r < 4; ++r) smaxl[w][l4 * 4 + r] = pmax[r];
    }
    __syncthreads();
    float prob[2][4], psum[4];
#pragma unroll
    for (int r = 0; r < 4; ++r) {
      float gm = fmaxf(smaxl[band * 2][l4 * 4 + r], smaxl[band * 2 + 1][l4 * 4 + r]);
      float e0 = __expf((sacc[0][r] - gm) * INVS);
      float e1 = __expf((sacc[1][r] - gm) * INVS);
      prob[0][r] = e0; prob[1][r] = e1;
      float ps = e0 + e1;
#pragma unroll
      for (int msk = 1; msk <= 8; msk <<= 1) ps += __shfl_xor(ps, msk, 64);
      psum[r] = ps;
    }
    if (l15 == 0) {
#pragma unroll
      for (int r = 0; r < 4; ++r) ssuml[w][l4 * 4 + r] = psum[r];
    }
    __syncthreads();
#pragma unroll
    for (int r = 0; r < 4; ++r) {
      float gs = ssuml[band * 2][l4 * 4 + r] + ssuml[band * 2 + 1][l4 * 4 + r];
      float is = 1.f / gs;
      int row = band * 16 + l4 * 4 + r;
      pb[row * 72 + (half * 2 + 0) * 16 + l15] = f2bf(prob[0][r] * is);
      pb[row * 72 + (half * 2 + 1) * 16 + l15] = f2bf(prob[1][r] * is);
    }
    __syncthreads();

    // ---- ao = p v: wave (band, s-half): sf 0..4 / 5..8 (compile-time unroll) ----
    f32x4 aoacc[5] = {};
    {
      const unsigned short* prow = &pb[(band * 16 + l15) * 72 + l4 * 8];
#pragma unroll
      for (int kk = 0; kk < 2; ++kk) {
        bf16x8 avv = *(const bf16x8*)&prow[kk * 32];
        if (half == 0) {
#pragma unroll
          for (int s = 0; s < 5; ++s) {
            bf16x8 bvv = *(const bf16x8*)&vT[(s * 16 + l15) * 72 + l4 * 8 + kk * 32];
            aoacc[s] = __builtin_amdgcn_mfma_f32_16x16x32_bf16(avv, bvv, aoacc[s], 0, 0, 0);
          }
        } else {
#pragma unroll
          for (int s = 0; s < 4; ++s) {
            bf16x8 bvv = *(const bf16x8*)&vT[((5 + s) * 16 + l15) * 72 + l4 * 8 + kk * 32];
            aoacc[s] = __builtin_amdgcn_mfma_f32_16x16x32_bf16(avv, bvv, aoacc[s], 0, 0, 0);
          }
        }
      }
    }
    // ---- partial row stats (this wave's s-range) ----
#pragma unroll
    for (int r = 0; r < 4; ++r) {
      int row = band * 16 + l4 * 4 + r;
      float s1 = 0.f, s2 = 0.f, sdt = 0.f;
      if (half == 0) {
#pragma unroll
        for (int s = 0; s < 5; ++s) {     // cols 0..79, all < 130
          int col = s * 16 + l15;
          float v = aoacc[s][r];
          s1 += v; s2 += v * v; sdt += v * b2f(AW_l[row * 136 + col]);
        }
      } else {
#pragma unroll
        for (int s = 0; s < 4; ++s) {     // cols 80..143, guard < 130
          int col = (5 + s) * 16 + l15;
          float v = aoacc[s][r];
          if (col < 130) { s1 += v; s2 += v * v; sdt += v * b2f(AW_l[row * 136 + col]); }
        }
      }
#pragma unroll
      for (int msk = 1; msk <= 8; msk <<= 1) {
        s1 += __shfl_xor(s1, msk, 64);
        s2 += __shfl_xor(s2, msk, 64);
        sdt += __shfl_xor(sdt, msk, 64);
      }
      if (l15 == 0) {
        stred[w][l4 * 4 + r][0] = s1;
        stred[w][l4 * 4 + r][1] = s2;
        stred[w][l4 * 4 + r][2] = sdt;
      }
    }
    __syncthreads();
    // ---- finalize (wave 0) ----
    if (tid < 64) {
      int row = tid, bnd = row >> 4, rr = row & 15;
      float s1  = stred[bnd * 2][rr][0] + stred[bnd * 2 + 1][rr][0];
      float s2  = stred[bnd * 2][rr][1] + stred[bnd * 2 + 1][rr][1];
      float sdt = stred[bnd * 2][rr][2] + stred[bnd * 2 + 1][rr][2];
      float mz  = 2.f * s1 * (1.f / 130.f);
      float ez2 = 4.f * s2 * (1.f / 130.f);
      float sg  = sqrtf(fmaxf(ez2 - mz * mz, 0.f));
      float i2  = 1.f / (sg + EPSF);
      float val = (2.f * sdt - mz * Paw[row]) * i2;
#pragma unroll
      for (int msk = 1; msk <= 32; msk <<= 1) val += __shfl_xor(val, msk, 64);
      if (tid == 0) out[b * 64 + n] = val + ccv;
    }
  }
}

// ---------------- host launch ----------------
extern "C" void kernel_launch(void* const* d_in, const int* in_sizes, int n_in,
                              void* d_out, int out_size, void* d_ws, size_t ws_size,
                              hipStream_t stream) {
  const float* sp     = (const float*)d_in[0];
  const float* h1     = (const float*)d_in[1];
  const float* h2     = (const float*)d_in[2];
  const float* Wq     = (const float*)d_in[3];
  const float* bq     = (const float*)d_in[4];
  const float* Wk     = (const float*)d_in[5];
  const float* bk     = (const float*)d_in[6];
  const float* Wv     = (const float*)d_in[7];
  const float* bv     = (const float*)d_in[8];
  const float* alpha1 = (const float*)d_in[9];
  const float* beta1  = (const float*)d_in[10];
  const float* alpha2 = (const float*)d_in[11];
  const float* beta2  = (const float*)d_in[12];
  const float* Wlin   = (const float*)d_in[13];
  const float* blin   = (const float*)d_in[14];
  float* out = (float*)d_out;

  unsigned short* UqkB = (unsigned short*)d_ws;     // 256*2*64*136 = 4,456,448
  unsigned short* UvB  = UqkB + 4456448;            // 256*136*64   = 2,228,224
  unsigned short* ABqk = UvB + 2228224;             // 2*64*272     = 34,816
  unsigned short* ABv  = ABqk + 34816;              // 136*128      = 17,408
  unsigned short* AWb  = ABv + 17408;               // 64*136       = 8,704
  float* S1g = (float*)(AWb + 8704);                // 16384
  float* S2g = S1g + 16384;                         // 16384
  float* Paw = S2g + 16384;                         // 64
  float* Ccw = Paw + 64;                            // 1   -> total ~13.6 MB

  k0<<<dim3(7), dim3(256), 0, stream>>>(alpha1, beta1, alpha2, beta2,
                                        Wq, bq, Wk, bk, Wv, bv, Wlin, blin,
                                        ABqk, ABv, AWb, Paw, Ccw);
  k1<<<dim3(256), dim3(256), 0, stream>>>(h1, h2, sp, alpha1, Wq, Wk, Wv,
                                          UqkB, UvB, S1g, S2g);
  k2<<<dim3(256), dim3(512), 0, stream>>>(h2, alpha1, UqkB, UvB, ABqk, ABv, AWb,
                                          S1g, S2g, Paw, Ccw,
                                          Wq, Wk, Wv, out);
}